// Round 3
// baseline (311.879 us; speedup 1.0000x reference)
//
#include <hip/hip_runtime.h>
#include <stdint.h>

typedef __bf16 bf16_t;
typedef __bf16 bf16x8 __attribute__((ext_vector_type(8)));
typedef float  f32x4  __attribute__((ext_vector_type(4)));

#define D_MODEL 1024
#define SEQ     2048
#define BATCH   2
#define NHEAD   16
#define DHEAD   64
#define NROWS   (BATCH*SEQ)   // 4096
#define LDK     40            // padded LDS K-stride (elements): 2-way-max bank aliasing

__device__ __forceinline__ bf16x8 cvt8(f32x4 lo, f32x4 hi) {
    bf16x8 o;
#pragma unroll
    for (int i = 0; i < 4; ++i) { o[i] = (bf16_t)lo[i]; o[4 + i] = (bf16_t)hi[i]; }
    return o;
}

// ---------------------------------------------------------------------------
// 128x128 GEMM tile: Y[m][n] = sum_k X[m][k] * W[n][k]   (Y = X @ W^T)
// 256 threads = 4 waves as 2x2 of 64x64 sub-tiles; BK=32; mfma 16x16x32 bf16.
// A operand: f32 (input x / f32 buffers) or bf16 (attention output in ws).
// B operand: always f32 weights. Output: bf16 (to ws) or f32 (final d_out).
// ---------------------------------------------------------------------------
template <bool A_F32, bool OUT_F32>
__device__ __forceinline__ void gemm128(const void* __restrict__ Xv,
                                        const float* __restrict__ W,
                                        void* __restrict__ Yv,
                                        int m0, int n0)
{
    __shared__ __align__(16) bf16_t lA[128 * LDK];
    __shared__ __align__(16) bf16_t lB[128 * LDK];

    const int tid  = threadIdx.x;
    const int lane = tid & 63;
    const int w    = tid >> 6;
    const int l15  = lane & 15;
    const int quad = lane >> 4;

    // staging: 512 8-element chunks per matrix per tile, 2 per thread
    const int c0 = tid, c1 = tid + 256;
    const int r0 = c0 >> 2, ks0 = c0 & 3;     // row 0..63,  chunk 0..3
    const int r1 = c1 >> 2, ks1 = c1 & 3;     // row 64..127
    const int sO0 = r0 * LDK + ks0 * 8, sO1 = r1 * LDK + ks1 * 8;

    const float*  gB0 = W + (size_t)(n0 + r0) * D_MODEL + ks0 * 8;
    const float*  gB1 = W + (size_t)(n0 + r1) * D_MODEL + ks1 * 8;
    const float*  gAf0 = (const float*)Xv  + (size_t)(m0 + r0) * D_MODEL + ks0 * 8;
    const float*  gAf1 = (const float*)Xv  + (size_t)(m0 + r1) * D_MODEL + ks1 * 8;
    const bf16_t* gAh0 = (const bf16_t*)Xv + (size_t)(m0 + r0) * D_MODEL + ks0 * 8;
    const bf16_t* gAh1 = (const bf16_t*)Xv + (size_t)(m0 + r1) * D_MODEL + ks1 * 8;

    // fragment read offsets
    int am[4], bn[4];
    const int mw = (w >> 1) * 64, nw = (w & 1) * 64;
#pragma unroll
    for (int i = 0; i < 4; ++i) {
        am[i] = (mw + i * 16 + l15) * LDK + quad * 8;
        bn[i] = (nw + i * 16 + l15) * LDK + quad * 8;
    }

    f32x4 acc[4][4];
#pragma unroll
    for (int i = 0; i < 4; ++i)
#pragma unroll
        for (int j = 0; j < 4; ++j) acc[i][j] = f32x4{0.f, 0.f, 0.f, 0.f};

    for (int k0 = 0; k0 < D_MODEL; k0 += 32) {
        // global loads into registers (overlap prior iteration's LDS reads)
        bf16x8 a0, a1;
        if constexpr (A_F32) {
            const float* p0 = gAf0 + k0;
            const float* p1 = gAf1 + k0;
            a0 = cvt8(*(const f32x4*)p0, *(const f32x4*)(p0 + 4));
            a1 = cvt8(*(const f32x4*)p1, *(const f32x4*)(p1 + 4));
        } else {
            a0 = *(const bf16x8*)(gAh0 + k0);
            a1 = *(const bf16x8*)(gAh1 + k0);
        }
        const float* q0p = gB0 + k0;
        const float* q1p = gB1 + k0;
        bf16x8 b0 = cvt8(*(const f32x4*)q0p, *(const f32x4*)(q0p + 4));
        bf16x8 b1 = cvt8(*(const f32x4*)q1p, *(const f32x4*)(q1p + 4));

        __syncthreads();                       // prior iteration's readers done
        *(bf16x8*)&lA[sO0] = a0;
        *(bf16x8*)&lA[sO1] = a1;
        *(bf16x8*)&lB[sO0] = b0;
        *(bf16x8*)&lB[sO1] = b1;
        __syncthreads();                       // stores visible

        bf16x8 af[4], bfr[4];
#pragma unroll
        for (int i = 0; i < 4; ++i) af[i]  = *(const bf16x8*)&lA[am[i]];
#pragma unroll
        for (int i = 0; i < 4; ++i) bfr[i] = *(const bf16x8*)&lB[bn[i]];
#pragma unroll
        for (int mi = 0; mi < 4; ++mi)
#pragma unroll
            for (int ni = 0; ni < 4; ++ni)
                acc[mi][ni] = __builtin_amdgcn_mfma_f32_16x16x32_bf16(
                    af[mi], bfr[ni], acc[mi][ni], 0, 0, 0);
    }

    // epilogue: C/D layout col = lane&15, row = quad*4 + reg  (m89-verified)
#pragma unroll
    for (int mi = 0; mi < 4; ++mi)
#pragma unroll
        for (int ni = 0; ni < 4; ++ni)
#pragma unroll
            for (int r = 0; r < 4; ++r) {
                int row = m0 + mw + mi * 16 + quad * 4 + r;
                int col = n0 + nw + ni * 16 + l15;
                if constexpr (OUT_F32)
                    ((float*)Yv)[(size_t)row * D_MODEL + col] = acc[mi][ni][r];
                else
                    ((bf16_t*)Yv)[(size_t)row * D_MODEL + col] = (bf16_t)acc[mi][ni][r];
            }
}

__global__ void __launch_bounds__(256)
k_gemm_qkv(const float* __restrict__ X,
           const float* __restrict__ Wq, const float* __restrict__ Wk,
           const float* __restrict__ Wv,
           bf16_t* __restrict__ Qb, bf16_t* __restrict__ Kb, bf16_t* __restrict__ Vb)
{
    const int sel = blockIdx.y >> 3;           // 0=Q 1=K 2=V
    const int n0  = (blockIdx.y & 7) * 128;
    const float* W = (sel == 0) ? Wq : (sel == 1) ? Wk : Wv;
    bf16_t*      Y = (sel == 0) ? Qb : (sel == 1) ? Kb : Vb;
    gemm128<true, false>(X, W, Y, blockIdx.x * 128, n0);
}

__global__ void __launch_bounds__(256)
k_gemm_out(const bf16_t* __restrict__ X, const float* __restrict__ W,
           float* __restrict__ Y)
{
    gemm128<false, true>(X, W, Y, blockIdx.x * 128, blockIdx.y * 128);
}

// ---------------------------------------------------------------------------
// Flash attention: block = (b,h, 64-row Q tile), 256 threads = 4 waves,
// each wave owns a 16-row Q strip. KV tiles of 64 rows, online softmax.
// P round-trips LDS (C-layout -> A-layout, m120); V transposed into LDS.
// Ob may alias Qb: each block reads exactly the Q slice it later writes,
// reads complete (in-register qf0/qf1) before any store; slices are
// block-disjoint, so no cross-block hazard.
// ---------------------------------------------------------------------------
__global__ void __launch_bounds__(256)
k_attn(const bf16_t* __restrict__ Qb, const bf16_t* __restrict__ Kb,
       const bf16_t* __restrict__ Vb, bf16_t* __restrict__ Ob)
{
    __shared__ __align__(16) bf16_t Vt[64 * 72];     // Vt[dh][j], stride 72
    __shared__ __align__(16) bf16_t Pl[4 * 16 * 72]; // per-wave 16x64 P strip

    const int tid  = threadIdx.x;
    const int lane = tid & 63;
    const int w    = tid >> 6;
    const int l15  = lane & 15;
    const int quad = lane >> 4;

    const int bh = blockIdx.x;            // 0..31
    const int b  = bh >> 4, h = bh & 15;
    const int q0 = blockIdx.y * 64;
    const float scale = 0.125f;           // 1/sqrt(64)

    const size_t base = (size_t)b * SEQ * D_MODEL + (size_t)h * DHEAD;
    const bf16_t* Qp = Qb + base;
    const bf16_t* Kp = Kb + base;
    const bf16_t* Vp = Vb + base;

    // Q fragments (A-operand: m=lane&15, k=quad*8+j), held for whole kernel
    const int qrow = q0 + w * 16 + l15;
    const bf16x8 qf0 = *(const bf16x8*)&Qp[(size_t)qrow * D_MODEL + quad * 8];
    const bf16x8 qf1 = *(const bf16x8*)&Qp[(size_t)qrow * D_MODEL + 32 + quad * 8];

    f32x4 acc_o[4];
#pragma unroll
    for (int dt = 0; dt < 4; ++dt) acc_o[dt] = f32x4{0.f, 0.f, 0.f, 0.f};
    float m_i[4] = {-1e30f, -1e30f, -1e30f, -1e30f};
    float l_i[4] = {0.f, 0.f, 0.f, 0.f};

    for (int kv0 = 0; kv0 < SEQ; kv0 += 64) {
        __syncthreads();  // previous iteration's Vt/Pl readers done

        // ---- stage V tile transposed: Vt[dh][j]
        {
            bf16x8 va = *(const bf16x8*)&Vp[(size_t)(kv0 + lane) * D_MODEL + w * 8];
            bf16x8 vb = *(const bf16x8*)&Vp[(size_t)(kv0 + lane) * D_MODEL + (4 + w) * 8];
#pragma unroll
            for (int u = 0; u < 8; ++u) Vt[(w * 8 + u) * 72 + lane] = va[u];
#pragma unroll
            for (int u = 0; u < 8; ++u) Vt[((4 + w) * 8 + u) * 72 + lane] = vb[u];
        }

        // ---- S = Q K^T for this wave's 16x64 strip
        f32x4 accs[4];
#pragma unroll
        for (int jt = 0; jt < 4; ++jt) accs[jt] = f32x4{0.f, 0.f, 0.f, 0.f};
#pragma unroll
        for (int jt = 0; jt < 4; ++jt) {
            const int krow = kv0 + jt * 16 + l15;
            bf16x8 kf0 = *(const bf16x8*)&Kp[(size_t)krow * D_MODEL + quad * 8];
            bf16x8 kf1 = *(const bf16x8*)&Kp[(size_t)krow * D_MODEL + 32 + quad * 8];
            accs[jt] = __builtin_amdgcn_mfma_f32_16x16x32_bf16(qf0, kf0, accs[jt], 0, 0, 0);
            accs[jt] = __builtin_amdgcn_mfma_f32_16x16x32_bf16(qf1, kf1, accs[jt], 0, 0, 0);
        }

        // ---- online softmax; S element: row=quad*4+reg (strip), col=jt*16+l15
        float alpha[4];
#pragma unroll
        for (int r = 0; r < 4; ++r) {
            float rm = -1e30f;
#pragma unroll
            for (int jt = 0; jt < 4; ++jt) rm = fmaxf(rm, accs[jt][r] * scale);
#pragma unroll
            for (int off = 1; off < 16; off <<= 1) rm = fmaxf(rm, __shfl_xor(rm, off));
            const float mn = fmaxf(m_i[r], rm);
            alpha[r] = __expf(m_i[r] - mn);
            m_i[r] = mn;
            float rs = 0.f;
#pragma unroll
            for (int jt = 0; jt < 4; ++jt) {
                float p = __expf(accs[jt][r] * scale - mn);
                Pl[w * 1152 + (quad * 4 + r) * 72 + jt * 16 + l15] = (bf16_t)p;
                rs += p;
            }
#pragma unroll
            for (int off = 1; off < 16; off <<= 1) rs += __shfl_xor(rs, off);
            l_i[r] = l_i[r] * alpha[r] + rs;
        }
#pragma unroll
        for (int dt = 0; dt < 4; ++dt)
#pragma unroll
            for (int r = 0; r < 4; ++r) acc_o[dt][r] *= alpha[r];

        __syncthreads();  // Vt staged by all waves; Pl writes visible to self

        // ---- O += P @ V : A-frag from Pl, B-frag from Vt
        const bf16x8 pf0 = *(const bf16x8*)&Pl[w * 1152 + l15 * 72 + quad * 8];
        const bf16x8 pf1 = *(const bf16x8*)&Pl[w * 1152 + l15 * 72 + 32 + quad * 8];
#pragma unroll
        for (int dt = 0; dt < 4; ++dt) {
            bf16x8 v0 = *(const bf16x8*)&Vt[(dt * 16 + l15) * 72 + quad * 8];
            bf16x8 v1 = *(const bf16x8*)&Vt[(dt * 16 + l15) * 72 + 32 + quad * 8];
            acc_o[dt] = __builtin_amdgcn_mfma_f32_16x16x32_bf16(pf0, v0, acc_o[dt], 0, 0, 0);
            acc_o[dt] = __builtin_amdgcn_mfma_f32_16x16x32_bf16(pf1, v1, acc_o[dt], 0, 0, 0);
        }
    }

    // ---- epilogue: O / l, write to plain [b*S+s][h*64+dh]
#pragma unroll
    for (int dt = 0; dt < 4; ++dt)
#pragma unroll
        for (int r = 0; r < 4; ++r) {
            int row = b * SEQ + q0 + w * 16 + quad * 4 + r;
            int col = h * DHEAD + dt * 16 + l15;
            Ob[(size_t)row * D_MODEL + col] = (bf16_t)(acc_o[dt][r] / l_i[r]);
        }
}

// ---------------------------------------------------------------------------
extern "C" void kernel_launch(void* const* d_in, const int* in_sizes, int n_in,
                              void* d_out, int out_size, void* d_ws, size_t ws_size,
                              hipStream_t stream)
{
    const float* x  = (const float*)d_in[0];
    const float* Wq = (const float*)d_in[1];
    const float* Wk = (const float*)d_in[2];
    const float* Wv = (const float*)d_in[3];
    const float* Wo = (const float*)d_in[4];
    float* out = (float*)d_out;

    const size_t mat = (size_t)NROWS * D_MODEL;   // 4,194,304 elements
    bf16_t* Qb = (bf16_t*)d_ws;
    bf16_t* Kb = Qb + mat;
    bf16_t* Vb = Kb + mat;
    bf16_t* Ab = Qb;                               // safe aliasing (see k_attn)

    dim3 blk(256);
    k_gemm_qkv<<<dim3(32, 24), blk, 0, stream>>>(x, Wq, Wk, Wv, Qb, Kb, Vb);
    k_attn<<<dim3(32, 32), blk, 0, stream>>>(Qb, Kb, Vb, Ab);
    k_gemm_out<<<dim3(32, 8), blk, 0, stream>>>(Ab, Wo, out);
}